// Round 1
// baseline (3946.862 us; speedup 1.0000x reference)
//
#include <hip/hip_runtime.h>
#include <math.h>

#define N_NODES 512
#define NE      4096
#define H       128
#define HH      1024
#define RBFK    64

// ---------------- small prep kernels ----------------

__global__ void k_extract(const int* __restrict__ ei, int* __restrict__ src, int* __restrict__ tgt) {
    // Detect int64 vs int32 storage: if int64, every odd int32 word (high word)
    // of the first 64 values is 0 (values are in [0,512)). If int32, those words
    // are src[1..127] — all-zero has probability ~(1/512)^64 ~ 0.
    __shared__ int s_is64;
    if (threadIdx.x == 0) {
        int any = 0;
        for (int i = 1; i < 128; i += 2) any |= ei[i];
        s_is64 = (any == 0) ? 1 : 0;
    }
    __syncthreads();
    int e = blockIdx.x * blockDim.x + threadIdx.x;
    if (e < NE) {
        if (s_is64) { src[e] = ei[2 * e]; tgt[e] = ei[2 * NE + 2 * e]; }
        else        { src[e] = ei[e];     tgt[e] = ei[NE + e];         }
    }
}

__global__ void k_hist(const int* __restrict__ src, int* __restrict__ cnt) {
    int e = blockIdx.x * blockDim.x + threadIdx.x;
    if (e < NE) atomicAdd(&cnt[src[e]], 1);
}

__global__ void k_scan(const int* __restrict__ cnt, int* __restrict__ segStart, int* __restrict__ cursor) {
    __shared__ int s[N_NODES];
    int t = threadIdx.x;
    s[t] = cnt[t];
    __syncthreads();
    for (int off = 1; off < N_NODES; off <<= 1) {
        int v = (t >= off) ? s[t - off] : 0;
        __syncthreads();
        s[t] += v;
        __syncthreads();
    }
    segStart[t + 1] = s[t];          // inclusive prefix
    if (t == 0) segStart[0] = 0;
    cursor[t] = s[t] - cnt[t];       // exclusive prefix
}

__global__ void k_scatter(const int* __restrict__ src, const int* __restrict__ tgt,
                          const float* __restrict__ ew, int* __restrict__ cursor,
                          int* __restrict__ srcS, int* __restrict__ tgtS, float* __restrict__ ewS) {
    int e = blockIdx.x * blockDim.x + threadIdx.x;
    if (e < NE) {
        int n = src[e];
        int p = atomicAdd(&cursor[n], 1);
        srcS[p] = n;
        tgtS[p] = tgt[e];
        ewS[p]  = ew[e];
    }
}

__global__ void k_build_ai(const float* __restrict__ atom_embs,
                           const int* __restrict__ srcS, const int* __restrict__ tgtS,
                           const float* __restrict__ ewS,
                           float* __restrict__ aiS, float* __restrict__ ajS) {
    int idx = blockIdx.x * blockDim.x + threadIdx.x;   // over NE*H
    int p = idx >> 7, h = idx & 127;
    if (p >= NE) return;
    float ew = ewS[p];
    aiS[idx] = atom_embs[tgtS[p] * H + h] + ew;
    ajS[idx] = atom_embs[srcS[p] * H + h] + ew;
}

__global__ void k_rbf(const int* __restrict__ srcS, const int* __restrict__ tgtS,
                      const float* __restrict__ pos, float* __restrict__ rbf) {
    int idx = blockIdx.x * blockDim.x + threadIdx.x;   // over NE*RBFK
    int p = idx >> 6, k = idx & 63;
    if (p >= NE) return;
    int s = srcS[p], t = tgtS[p];
    float dx = pos[t * 3 + 0] - pos[s * 3 + 0];
    float dy = pos[t * 3 + 1] - pos[s * 3 + 1];
    float dz = pos[t * 3 + 2] - pos[s * 3 + 2];
    float d = sqrtf(dx * dx + dy * dy + dz * dz);
    float x = d * 0.1f;   // d / CUTOFF
    float cut = 0.0f;
    if (x < 1.0f) {
        float x3 = x * x * x, x4 = x3 * x, x5 = x4 * x;
        cut = 1.0f - 6.0f * x5 + 15.0f * x4 - 10.0f * x3;
    }
    // centers = linspace(1, e^-10, 64): c_k = 1 + k*(e^-10 - 1)/63
    float ck = 1.0f + (float)k * (-0.015872295239210119f);
    float tt = expf(-d) - ck;
    rbf[p * RBFK + k] = cut * expf(-1024.0929857f * tt * tt);
}

__global__ void k_eij(const float* __restrict__ hi, const float* __restrict__ hj,
                      float* __restrict__ eij) {
    int idx = blockIdx.x * blockDim.x + threadIdx.x;   // over NE*H
    int p = idx >> 7, h = idx & 127;
    if (p >= NE) return;
    float a = hi[idx], b = hj[idx];
    float* row = eij + (size_t)p * (3 * H);
    row[h]           = a + b;
    row[H + h]       = a - b;
    row[2 * H + h]   = a * b;
}

// ---------------- tiled f32 GEMMs ----------------
// All M multiples of 64, N multiples of 64, K multiples of 16 — no guards needed.

#define BM 64
#define BN 64
#define BK 16

__global__ __launch_bounds__(256) void gemm_nn(
    const float* __restrict__ A, int lda,
    const float* __restrict__ B, int ldb,
    float* __restrict__ C, int ldc,
    int K, float alpha, const float* __restrict__ bias, int acc)
{
    __shared__ float As[BK][BM + 1];
    __shared__ float Bs[BK][BN + 1];
    int tid = threadIdx.x;
    int tx = tid & 15, ty = tid >> 4;
    int row0 = blockIdx.y * BM, col0 = blockIdx.x * BN;
    float accv[4][4] = {};
    for (int k0 = 0; k0 < K; k0 += BK) {
        for (int i = tid; i < BM * BK; i += 256) {
            int r = i >> 4, c = i & 15;
            As[c][r] = A[(size_t)(row0 + r) * lda + k0 + c];
        }
        for (int i = tid; i < BK * BN; i += 256) {
            int r = i >> 6, c = i & 63;
            Bs[r][c] = B[(size_t)(k0 + r) * ldb + col0 + c];
        }
        __syncthreads();
#pragma unroll
        for (int kk = 0; kk < BK; kk++) {
            float a[4], b[4];
#pragma unroll
            for (int i = 0; i < 4; i++) a[i] = As[kk][ty * 4 + i];
#pragma unroll
            for (int j = 0; j < 4; j++) b[j] = Bs[kk][tx * 4 + j];
#pragma unroll
            for (int i = 0; i < 4; i++)
#pragma unroll
                for (int j = 0; j < 4; j++) accv[i][j] = fmaf(a[i], b[j], accv[i][j]);
        }
        __syncthreads();
    }
#pragma unroll
    for (int i = 0; i < 4; i++) {
        int r = row0 + ty * 4 + i;
#pragma unroll
        for (int j = 0; j < 4; j++) {
            int cc = col0 + tx * 4 + j;
            float v = accv[i][j] * alpha;
            if (bias) v += bias[cc];
            size_t o = (size_t)r * ldc + cc;
            if (acc) v += C[o];
            C[o] = v;
        }
    }
}

// C[i,j] = sum_k A[i,k] * B[j,k]   (both row-major, "NT")
__global__ __launch_bounds__(256) void gemm_nt(
    const float* __restrict__ A, int lda,
    const float* __restrict__ B, int ldb,
    float* __restrict__ C, int ldc, int K)
{
    __shared__ float As[BK][BM + 1];
    __shared__ float Bs[BK][BN + 1];
    int tid = threadIdx.x;
    int tx = tid & 15, ty = tid >> 4;
    int row0 = blockIdx.y * BM, col0 = blockIdx.x * BN;
    float accv[4][4] = {};
    for (int k0 = 0; k0 < K; k0 += BK) {
        for (int i = tid; i < BM * BK; i += 256) {
            int r = i >> 4, c = i & 15;
            As[c][r] = A[(size_t)(row0 + r) * lda + k0 + c];
        }
        for (int i = tid; i < BN * BK; i += 256) {
            int r = i >> 4, c = i & 15;
            Bs[c][r] = B[(size_t)(col0 + r) * ldb + k0 + c];
        }
        __syncthreads();
#pragma unroll
        for (int kk = 0; kk < BK; kk++) {
            float a[4], b[4];
#pragma unroll
            for (int i = 0; i < 4; i++) a[i] = As[kk][ty * 4 + i];
#pragma unroll
            for (int j = 0; j < 4; j++) b[j] = Bs[kk][tx * 4 + j];
#pragma unroll
            for (int i = 0; i < 4; i++)
#pragma unroll
                for (int j = 0; j < 4; j++) accv[i][j] = fmaf(a[i], b[j], accv[i][j]);
        }
        __syncthreads();
    }
#pragma unroll
    for (int i = 0; i < 4; i++) {
        size_t r = (size_t)(row0 + ty * 4 + i);
#pragma unroll
        for (int j = 0; j < 4; j++) C[r * ldc + col0 + tx * 4 + j] = accv[i][j];
    }
}

// ---------------- segment softmax over contiguous (sorted) columns ----------------
// One block per logits row; segments along columns are contiguous after sort-by-src.
__global__ __launch_bounds__(256) void k_softmax(float* __restrict__ L, const int* __restrict__ segStart) {
    __shared__ float row[NE];
    float* lr = L + (size_t)blockIdx.x * NE;
    for (int i = threadIdx.x; i < NE; i += 256) row[i] = lr[i];
    __syncthreads();
    for (int n = threadIdx.x; n < N_NODES; n += 256) {
        int a = segStart[n], b = segStart[n + 1];
        if (a >= b) continue;
        float m = -1e30f;
        for (int p = a; p < b; p++) m = fmaxf(m, row[p]);
        float s = 0.0f;
        for (int p = a; p < b; p++) { float e = expf(row[p] - m); row[p] = e; s += e; }
        float inv = 1.0f / s;
        for (int p = a; p < b; p++) row[p] *= inv;
    }
    __syncthreads();
    for (int i = threadIdx.x; i < NE; i += 256) lr[i] = row[i];
}

__global__ void k_scatter_add(const int* __restrict__ tgtS, const float* __restrict__ msg,
                              float* __restrict__ agg) {
    int idx = blockIdx.x * blockDim.x + threadIdx.x;   // over NE*H
    int p = idx >> 7, h = idx & 127;
    if (p >= NE) return;
    atomicAdd(&agg[tgtS[p] * H + h], msg[idx]);
}

// ---------------- LN + FFN + LN head ----------------
__global__ __launch_bounds__(128) void k_head(
    const float* __restrict__ agg,
    const float* __restrict__ ln_g, const float* __restrict__ ln_b,
    const float* __restrict__ f1_w, const float* __restrict__ f1_b,
    const float* __restrict__ f2_w, const float* __restrict__ f2_b,
    const float* __restrict__ f3_w, const float* __restrict__ f3_b,
    float* __restrict__ out)
{
    __shared__ float x[H];
    __shared__ float red[H];
    int t = threadIdx.x, row = blockIdx.x;
    float v = agg[row * H + t];
    // LayerNorm 1
    red[t] = v; __syncthreads();
    for (int s = 64; s > 0; s >>= 1) { if (t < s) red[t] += red[t + s]; __syncthreads(); }
    float mu = red[0] * (1.0f / H); __syncthreads();
    float dv = v - mu;
    red[t] = dv * dv; __syncthreads();
    for (int s = 64; s > 0; s >>= 1) { if (t < s) red[t] += red[t + s]; __syncthreads(); }
    float var = red[0] * (1.0f / H); __syncthreads();
    x[t] = dv * rsqrtf(var + 1e-5f) * ln_g[t] + ln_b[t];
    __syncthreads();
    // 3x (linear + softplus)
    const float* Ws[3] = { f1_w, f2_w, f3_w };
    const float* Bb[3] = { f1_b, f2_b, f3_b };
    for (int l = 0; l < 3; l++) {
        float acc = Bb[l][t];
        const float* Wl = Ws[l];
        for (int k = 0; k < H; k++) acc = fmaf(x[k], Wl[k * H + t], acc);
        float o = fmaxf(acc, 0.0f) + log1pf(expf(-fabsf(acc)));   // stable softplus
        __syncthreads();
        x[t] = o;
        __syncthreads();
    }
    // LayerNorm 2
    float xv = x[t];
    red[t] = xv; __syncthreads();
    for (int s = 64; s > 0; s >>= 1) { if (t < s) red[t] += red[t + s]; __syncthreads(); }
    mu = red[0] * (1.0f / H); __syncthreads();
    float dv2 = xv - mu;
    red[t] = dv2 * dv2; __syncthreads();
    for (int s = 64; s > 0; s >>= 1) { if (t < s) red[t] += red[t + s]; __syncthreads(); }
    var = red[0] * (1.0f / H);
    out[row * H + t] = dv2 * rsqrtf(var + 1e-5f) * ln_g[t] + ln_b[t];
}

// ---------------- launch ----------------

extern "C" void kernel_launch(void* const* d_in, const int* in_sizes, int n_in,
                              void* d_out, int out_size, void* d_ws, size_t ws_size,
                              hipStream_t stream) {
    const float* atom_embs   = (const float*)d_in[0];
    const float* pos         = (const float*)d_in[1];
    const float* edge_weight = (const float*)d_in[2];
    const int*   edge_idx    = (const int*)d_in[3];
    const float* Wq   = (const float*)d_in[4];
    const float* Wk   = (const float*)d_in[5];
    const float* Wv   = (const float*)d_in[6];
    const float* li_w = (const float*)d_in[7];
    const float* li_b = (const float*)d_in[8];
    const float* lj_w = (const float*)d_in[9];
    const float* lj_b = (const float*)d_in[10];
    const float* el_w = (const float*)d_in[11];
    const float* el_b = (const float*)d_in[12];
    const float* rl_w = (const float*)d_in[13];
    const float* rl_b = (const float*)d_in[14];
    const float* ol_w = (const float*)d_in[15];
    const float* ol_b = (const float*)d_in[16];
    const float* ln_g = (const float*)d_in[17];
    const float* ln_b = (const float*)d_in[18];
    const float* f1_w = (const float*)d_in[19];
    const float* f1_b = (const float*)d_in[20];
    const float* f2_w = (const float*)d_in[21];
    const float* f2_b = (const float*)d_in[22];
    const float* f3_w = (const float*)d_in[23];
    const float* f3_b = (const float*)d_in[24];
    float* out = (float*)d_out;

    char* w = (char*)d_ws;
    size_t off = 0;
    auto alloc = [&](size_t bytes) -> void* {
        void* p = w + off;
        off += (bytes + 255) & ~(size_t)255;
        return p;
    };
    int*   src      = (int*)alloc(NE * 4);
    int*   tgt      = (int*)alloc(NE * 4);
    int*   srcS     = (int*)alloc(NE * 4);
    int*   tgtS     = (int*)alloc(NE * 4);
    float* ewS      = (float*)alloc(NE * 4);
    int*   cnt      = (int*)alloc(N_NODES * 4);
    int*   cursor   = (int*)alloc(N_NODES * 4);
    int*   segStart = (int*)alloc((N_NODES + 1) * 4);
    float* aiS   = (float*)alloc((size_t)NE * H * 4);
    float* ajS   = (float*)alloc((size_t)NE * H * 4);
    float* Qs    = (float*)alloc((size_t)NE * HH * 4);
    float* Ks    = (float*)alloc((size_t)NE * HH * 4);
    float* feats = (float*)alloc((size_t)NE * HH * 4);
    float* hi    = (float*)alloc((size_t)NE * H * 4);
    float* hj    = (float*)alloc((size_t)NE * H * 4);
    float* eij   = (float*)alloc((size_t)NE * 3 * H * 4);
    float* rbf   = (float*)alloc((size_t)NE * RBFK * 4);
    float* G     = (float*)alloc((size_t)NE * H * 4);
    float* Lt    = (float*)alloc((size_t)1024 * NE * 4);   // one row-block of logits
    float* msg   = (float*)alloc((size_t)NE * H * 4);
    float* agg   = (float*)alloc((size_t)N_NODES * H * 4);

    hipMemsetAsync(cnt, 0, N_NODES * 4, stream);
    hipMemsetAsync(agg, 0, (size_t)N_NODES * H * 4, stream);

    k_extract<<<NE / 256, 256, 0, stream>>>(edge_idx, src, tgt);
    k_hist   <<<NE / 256, 256, 0, stream>>>(src, cnt);
    k_scan   <<<1, N_NODES, 0, stream>>>(cnt, segStart, cursor);
    k_scatter<<<NE / 256, 256, 0, stream>>>(src, tgt, edge_weight, cursor, srcS, tgtS, ewS);
    k_build_ai<<<NE * H / 256, 256, 0, stream>>>(atom_embs, srcS, tgtS, ewS, aiS, ajS);
    k_rbf    <<<NE * RBFK / 256, 256, 0, stream>>>(srcS, tgtS, pos, rbf);

    dim3 gQKV(HH / BN, NE / BM);
    // fold logits scale H^-0.5 into Q
    gemm_nn<<<gQKV, 256, 0, stream>>>(aiS, H, Wq, HH, Qs, HH, H, 0.08838834764831845f, nullptr, 0);
    gemm_nn<<<gQKV, 256, 0, stream>>>(aiS, H, Wk, HH, Ks, HH, H, 1.0f, nullptr, 0);
    gemm_nn<<<gQKV, 256, 0, stream>>>(aiS, H, Wv, HH, feats, HH, H, 1.0f, nullptr, 0);

    dim3 gHI(H / BN, NE / BM);
    gemm_nn<<<gHI, 256, 0, stream>>>(aiS, H, li_w, H, hi, H, H, 1.0f, li_b, 0);
    gemm_nn<<<gHI, 256, 0, stream>>>(ajS, H, lj_w, H, hj, H, H, 1.0f, lj_b, 0);
    k_eij<<<NE * H / 256, 256, 0, stream>>>(hi, hj, eij);

    gemm_nn<<<gQKV, 256, 0, stream>>>(eij, 3 * H, el_w, HH, feats, HH, 3 * H, 1.0f, el_b, 1);
    gemm_nn<<<gQKV, 256, 0, stream>>>(rbf, RBFK, rl_w, HH, feats, HH, RBFK, 1.0f, rl_b, 1);

    dim3 gG(H / BN, NE / BM);
    gemm_nn<<<gG, 256, 0, stream>>>(feats, HH, ol_w, H, G, H, HH, 1.0f, nullptr, 0);

    // logits / softmax / msg in 4 row-blocks of 1024
    for (int rb = 0; rb < 4; rb++) {
        const float* Arb = Qs + (size_t)rb * 1024 * HH;
        dim3 gL(NE / BN, 1024 / BM);
        gemm_nt<<<gL, 256, 0, stream>>>(Arb, HH, Ks, HH, Lt, NE, HH);
        k_softmax<<<1024, 256, 0, stream>>>(Lt, segStart);
        dim3 gM(H / BN, 1024 / BM);
        gemm_nn<<<gM, 256, 0, stream>>>(Lt, NE, G, H, msg + (size_t)rb * 1024 * H, H, NE, 1.0f, ol_b, 0);
    }

    k_scatter_add<<<NE * H / 256, 256, 0, stream>>>(tgtS, msg, agg);
    k_head<<<N_NODES, H, 0, stream>>>(agg, ln_g, ln_b, f1_w, f1_b, f2_w, f2_b, f3_w, f3_b, out);
}

// Round 2
// 497.520 us; speedup vs baseline: 7.9331x; 7.9331x over previous
//
#include <hip/hip_runtime.h>
#include <math.h>

#define N_NODES 512
#define NE      4096
#define H       128
#define HH      1024
#define RBFK    64

typedef __attribute__((ext_vector_type(8))) short bf16x8;
typedef __attribute__((ext_vector_type(4))) float f32x4;

__device__ __forceinline__ short f2bf(float x) {
    unsigned u = __builtin_bit_cast(unsigned, x);
    unsigned r = u + 0x7FFFu + ((u >> 16) & 1u);   // RNE
    return (short)(r >> 16);
}

__device__ __forceinline__ void gload16(const short* g, short* l) {
    __builtin_amdgcn_global_load_lds(
        (const __attribute__((address_space(1))) void*)g,
        (__attribute__((address_space(3))) void*)l, 16, 0, 0);
}

// ---------------- small prep kernels ----------------

__global__ void k_extract(const int* __restrict__ ei, int* __restrict__ src, int* __restrict__ tgt) {
    __shared__ int s_is64;
    if (threadIdx.x == 0) {
        int any = 0;
        for (int i = 1; i < 128; i += 2) any |= ei[i];
        s_is64 = (any == 0) ? 1 : 0;
    }
    __syncthreads();
    int e = blockIdx.x * blockDim.x + threadIdx.x;
    if (e < NE) {
        if (s_is64) { src[e] = ei[2 * e]; tgt[e] = ei[2 * NE + 2 * e]; }
        else        { src[e] = ei[e];     tgt[e] = ei[NE + e];         }
    }
}

__global__ void k_hist(const int* __restrict__ src, int* __restrict__ cnt) {
    int e = blockIdx.x * blockDim.x + threadIdx.x;
    if (e < NE) atomicAdd(&cnt[src[e]], 1);
}

__global__ void k_scan(const int* __restrict__ cnt, int* __restrict__ segStart, int* __restrict__ cursor) {
    __shared__ int s[N_NODES];
    int t = threadIdx.x;
    s[t] = cnt[t];
    __syncthreads();
    for (int off = 1; off < N_NODES; off <<= 1) {
        int v = (t >= off) ? s[t - off] : 0;
        __syncthreads();
        s[t] += v;
        __syncthreads();
    }
    segStart[t + 1] = s[t];
    if (t == 0) segStart[0] = 0;
    cursor[t] = s[t] - cnt[t];
}

__global__ void k_scatter(const int* __restrict__ src, const int* __restrict__ tgt,
                          const float* __restrict__ ew, int* __restrict__ cursor,
                          int* __restrict__ srcS, int* __restrict__ tgtS, float* __restrict__ ewS) {
    int e = blockIdx.x * blockDim.x + threadIdx.x;
    if (e < NE) {
        int n = src[e];
        int p = atomicAdd(&cursor[n], 1);
        srcS[p] = n;
        tgtS[p] = tgt[e];
        ewS[p]  = ew[e];
    }
}

__global__ void k_build_ai(const float* __restrict__ atom_embs,
                           const int* __restrict__ srcS, const int* __restrict__ tgtS,
                           const float* __restrict__ ewS,
                           short* __restrict__ aiB, short* __restrict__ ajB) {
    int idx = blockIdx.x * blockDim.x + threadIdx.x;   // NE*H
    int p = idx >> 7, h = idx & 127;
    if (p >= NE) return;
    float ew = ewS[p];
    aiB[idx] = f2bf(atom_embs[tgtS[p] * H + h] + ew);
    ajB[idx] = f2bf(atom_embs[srcS[p] * H + h] + ew);
}

__global__ void k_rbf(const int* __restrict__ srcS, const int* __restrict__ tgtS,
                      const float* __restrict__ pos, short* __restrict__ rbf) {
    int idx = blockIdx.x * blockDim.x + threadIdx.x;   // NE*RBFK
    int p = idx >> 6, k = idx & 63;
    if (p >= NE) return;
    int s = srcS[p], t = tgtS[p];
    float dx = pos[t * 3 + 0] - pos[s * 3 + 0];
    float dy = pos[t * 3 + 1] - pos[s * 3 + 1];
    float dz = pos[t * 3 + 2] - pos[s * 3 + 2];
    float d = sqrtf(dx * dx + dy * dy + dz * dz);
    float x = d * 0.1f;
    float cut = 0.0f;
    if (x < 1.0f) {
        float x3 = x * x * x, x4 = x3 * x, x5 = x4 * x;
        cut = 1.0f - 6.0f * x5 + 15.0f * x4 - 10.0f * x3;
    }
    float ck = 1.0f + (float)k * (-0.015872295239210119f);
    float tt = expf(-d) - ck;
    rbf[p * RBFK + k] = f2bf(cut * expf(-1024.0929857f * tt * tt));
}

__global__ void k_eij(const float* __restrict__ hi, const float* __restrict__ hj,
                      short* __restrict__ eij) {
    int idx = blockIdx.x * blockDim.x + threadIdx.x;   // NE*H
    int p = idx >> 7, h = idx & 127;
    if (p >= NE) return;
    float a = hi[idx], b = hj[idx];
    short* row = eij + (size_t)p * (3 * H);
    row[h]         = f2bf(a + b);
    row[H + h]     = f2bf(a - b);
    row[2 * H + h] = f2bf(a * b);
}

// transpose-and-convert: out[c*R + r] = bf16(in[r*C + c])
__global__ void k_transpose_b(const float* __restrict__ in, short* __restrict__ out, int R, int C) {
    int idx = blockIdx.x * blockDim.x + threadIdx.x;
    if (idx >= R * C) return;
    int r = idx / C, c = idx % C;
    out[(size_t)c * R + r] = f2bf(in[idx]);
}

__global__ void k_f2b(const float* __restrict__ in, short* __restrict__ out, int n) {
    int idx = blockIdx.x * blockDim.x + threadIdx.x;
    if (idx < n) out[idx] = f2bf(in[idx]);
}

// ---------------- bf16 MFMA NT GEMM (m97 structure) ----------------
// C[i,j] = alpha * sum_k A[i,k]*B[j,k]  (+bias[j]) (+C accum)
// A: M x K bf16 row-major, B: N x K bf16 row-major. M,N mult of 128, Kchunk mult of 64.
// OUTB=1 -> bf16 output; OUTB=0 -> f32 output (accum / split-K via blockIdx.z * split_pitch)

template<int OUTB>
__global__ __launch_bounds__(256) void mgemm(
    const short* __restrict__ A, int lda,
    const short* __restrict__ B, int ldb,
    void* __restrict__ Cp, int ldc,
    int K, float alpha, const float* __restrict__ bias,
    int accum, long split_pitch)
{
    __shared__ __align__(16) short As[128 * 64];
    __shared__ __align__(16) short Bs[128 * 64];
    const int tid = threadIdx.x;
    const int wave = tid >> 6, lane = tid & 63;
    const int row0 = blockIdx.y * 128, col0 = blockIdx.x * 128;
    const int kchunk = K / gridDim.z;
    const int kbeg = kchunk * blockIdx.z;
    const int kend = kbeg + kchunk;

    f32x4 acc[4][4];
#pragma unroll
    for (int i = 0; i < 4; i++)
#pragma unroll
        for (int j = 0; j < 4; j++) acc[i][j] = (f32x4){0.f, 0.f, 0.f, 0.f};

    const int m0 = (wave >> 1) * 64, n0 = (wave & 1) * 64;
    const int lr = lane >> 3;          // row within 8-row group
    const int lc = (lane & 7) * 8;     // col offset (shorts)
    const int cl = lane & 15, quad = lane >> 4;

    for (int k0 = kbeg; k0 < kend; k0 += 64) {
#pragma unroll
        for (int i = 0; i < 4; i++) {
            int r = wave * 32 + i * 8;
            gload16(A + (size_t)(row0 + r + lr) * lda + k0 + lc, As + r * 64);
            gload16(B + (size_t)(col0 + r + lr) * ldb + k0 + lc, Bs + r * 64);
        }
        __syncthreads();
#pragma unroll
        for (int kk = 0; kk < 64; kk += 32) {
            bf16x8 af[4], bf[4];
            int ko = kk + quad * 8;
#pragma unroll
            for (int i = 0; i < 4; i++)
                af[i] = *(const bf16x8*)(As + (m0 + i * 16 + cl) * 64 + ko);
#pragma unroll
            for (int j = 0; j < 4; j++)
                bf[j] = *(const bf16x8*)(Bs + (n0 + j * 16 + cl) * 64 + ko);
#pragma unroll
            for (int i = 0; i < 4; i++)
#pragma unroll
                for (int j = 0; j < 4; j++)
                    acc[i][j] = __builtin_amdgcn_mfma_f32_16x16x32_bf16(af[i], bf[j], acc[i][j], 0, 0, 0);
        }
        __syncthreads();
    }

    // epilogue: C/D layout col=lane&15, row=quad*4+reg
    if (OUTB) {
        short* C = (short*)Cp;
#pragma unroll
        for (int i = 0; i < 4; i++) {
#pragma unroll
            for (int j = 0; j < 4; j++) {
                int cc = col0 + n0 + j * 16 + cl;
                float bv = bias ? bias[cc] : 0.0f;
#pragma unroll
                for (int reg = 0; reg < 4; reg++) {
                    int rr = row0 + m0 + i * 16 + quad * 4 + reg;
                    C[(size_t)rr * ldc + cc] = f2bf(acc[i][j][reg] * alpha + bv);
                }
            }
        }
    } else {
        float* C = (float*)Cp + (size_t)blockIdx.z * split_pitch;
#pragma unroll
        for (int i = 0; i < 4; i++) {
#pragma unroll
            for (int j = 0; j < 4; j++) {
                int cc = col0 + n0 + j * 16 + cl;
                float bv = bias ? bias[cc] : 0.0f;
#pragma unroll
                for (int reg = 0; reg < 4; reg++) {
                    int rr = row0 + m0 + i * 16 + quad * 4 + reg;
                    size_t o = (size_t)rr * ldc + cc;
                    float v = acc[i][j][reg] * alpha + bv;
                    if (accum) v += C[o];
                    C[o] = v;
                }
            }
        }
    }
}

// ---------------- segment softmax (contiguous column segments), bf16 out ----------------
__global__ __launch_bounds__(256) void k_softmax_b(const float* __restrict__ L,
                                                   short* __restrict__ P,
                                                   const int* __restrict__ segStart) {
    __shared__ float row[NE];
    const float* lr = L + (size_t)blockIdx.x * NE;
    for (int i = threadIdx.x; i < NE; i += 256) row[i] = lr[i];
    __syncthreads();
    for (int n = threadIdx.x; n < N_NODES; n += 256) {
        int a = segStart[n], b = segStart[n + 1];
        if (a >= b) continue;
        float m = -1e30f;
        for (int p = a; p < b; p++) m = fmaxf(m, row[p]);
        float s = 0.0f;
        for (int p = a; p < b; p++) { float e = expf(row[p] - m); row[p] = e; s += e; }
        float inv = 1.0f / s;
        for (int p = a; p < b; p++) row[p] *= inv;
    }
    __syncthreads();
    short* pr = P + (size_t)blockIdx.x * NE;
    for (int i = threadIdx.x; i < NE; i += 256) pr[i] = f2bf(row[i]);
}

// sum 8 split-K partials + ol_b, scatter-add into agg by tgt
__global__ void k_scatter_rb(const int* __restrict__ tgtS, const float* __restrict__ msgP,
                             const float* __restrict__ ol_b, float* __restrict__ agg, int pbase) {
    int idx = blockIdx.x * blockDim.x + threadIdx.x;   // 1024*H
    int p = idx >> 7, h = idx & 127;
    if (p >= 1024) return;
    float s = ol_b[h];
#pragma unroll
    for (int z = 0; z < 8; z++) s += msgP[(size_t)z * 1024 * H + idx];
    atomicAdd(&agg[tgtS[pbase + p] * H + h], s);
}

// ---------------- LN + FFN + LN head ----------------
__global__ __launch_bounds__(128) void k_head(
    const float* __restrict__ agg,
    const float* __restrict__ ln_g, const float* __restrict__ ln_b,
    const float* __restrict__ f1_w, const float* __restrict__ f1_b,
    const float* __restrict__ f2_w, const float* __restrict__ f2_b,
    const float* __restrict__ f3_w, const float* __restrict__ f3_b,
    float* __restrict__ out)
{
    __shared__ float x[H];
    __shared__ float red[H];
    int t = threadIdx.x, row = blockIdx.x;
    float v = agg[row * H + t];
    red[t] = v; __syncthreads();
    for (int s = 64; s > 0; s >>= 1) { if (t < s) red[t] += red[t + s]; __syncthreads(); }
    float mu = red[0] * (1.0f / H); __syncthreads();
    float dv = v - mu;
    red[t] = dv * dv; __syncthreads();
    for (int s = 64; s > 0; s >>= 1) { if (t < s) red[t] += red[t + s]; __syncthreads(); }
    float var = red[0] * (1.0f / H); __syncthreads();
    x[t] = dv * rsqrtf(var + 1e-5f) * ln_g[t] + ln_b[t];
    __syncthreads();
    const float* Ws[3] = { f1_w, f2_w, f3_w };
    const float* Bb[3] = { f1_b, f2_b, f3_b };
    for (int l = 0; l < 3; l++) {
        float acc = Bb[l][t];
        const float* Wl = Ws[l];
        for (int k = 0; k < H; k++) acc = fmaf(x[k], Wl[k * H + t], acc);
        float o = fmaxf(acc, 0.0f) + log1pf(expf(-fabsf(acc)));
        __syncthreads();
        x[t] = o;
        __syncthreads();
    }
    float xv = x[t];
    red[t] = xv; __syncthreads();
    for (int s = 64; s > 0; s >>= 1) { if (t < s) red[t] += red[t + s]; __syncthreads(); }
    mu = red[0] * (1.0f / H); __syncthreads();
    float dv2 = xv - mu;
    red[t] = dv2 * dv2; __syncthreads();
    for (int s = 64; s > 0; s >>= 1) { if (t < s) red[t] += red[t + s]; __syncthreads(); }
    var = red[0] * (1.0f / H);
    out[row * H + t] = dv2 * rsqrtf(var + 1e-5f) * ln_g[t] + ln_b[t];
}

// ---------------- launch ----------------

extern "C" void kernel_launch(void* const* d_in, const int* in_sizes, int n_in,
                              void* d_out, int out_size, void* d_ws, size_t ws_size,
                              hipStream_t stream) {
    const float* atom_embs   = (const float*)d_in[0];
    const float* pos         = (const float*)d_in[1];
    const float* edge_weight = (const float*)d_in[2];
    const int*   edge_idx    = (const int*)d_in[3];
    const float* Wq   = (const float*)d_in[4];
    const float* Wk   = (const float*)d_in[5];
    const float* Wv   = (const float*)d_in[6];
    const float* li_w = (const float*)d_in[7];
    const float* li_b = (const float*)d_in[8];
    const float* lj_w = (const float*)d_in[9];
    const float* lj_b = (const float*)d_in[10];
    const float* el_w = (const float*)d_in[11];
    const float* el_b = (const float*)d_in[12];
    const float* rl_w = (const float*)d_in[13];
    const float* rl_b = (const float*)d_in[14];
    const float* ol_w = (const float*)d_in[15];
    const float* ol_b = (const float*)d_in[16];
    const float* ln_g = (const float*)d_in[17];
    const float* ln_b = (const float*)d_in[18];
    const float* f1_w = (const float*)d_in[19];
    const float* f1_b = (const float*)d_in[20];
    const float* f2_w = (const float*)d_in[21];
    const float* f2_b = (const float*)d_in[22];
    const float* f3_w = (const float*)d_in[23];
    const float* f3_b = (const float*)d_in[24];
    float* out = (float*)d_out;

    char* w = (char*)d_ws;
    size_t off = 0;
    auto alloc = [&](size_t bytes) -> void* {
        void* p = w + off;
        off += (bytes + 255) & ~(size_t)255;
        return p;
    };
    int*   src      = (int*)alloc(NE * 4);
    int*   tgt      = (int*)alloc(NE * 4);
    int*   srcS     = (int*)alloc(NE * 4);
    int*   tgtS     = (int*)alloc(NE * 4);
    float* ewS      = (float*)alloc(NE * 4);
    int*   cnt      = (int*)alloc(N_NODES * 4);
    int*   cursor   = (int*)alloc(N_NODES * 4);
    int*   segStart = (int*)alloc((N_NODES + 1) * 4);
    short* aiB    = (short*)alloc((size_t)NE * H * 2);
    short* ajB    = (short*)alloc((size_t)NE * H * 2);
    float* hi     = (float*)alloc((size_t)NE * H * 4);
    float* hj     = (float*)alloc((size_t)NE * H * 4);
    short* eijB   = (short*)alloc((size_t)NE * 3 * H * 2);
    short* rbfB   = (short*)alloc((size_t)NE * RBFK * 2);
    short* QB     = (short*)alloc((size_t)NE * HH * 2);
    short* KB     = (short*)alloc((size_t)NE * HH * 2);
    float* feats  = (float*)alloc((size_t)NE * HH * 4);
    short* featsB = (short*)alloc((size_t)NE * HH * 2);
    short* GT     = (short*)alloc((size_t)H * NE * 2);
    float* Lt     = (float*)alloc((size_t)1024 * NE * 4);
    short* prodB  = (short*)alloc((size_t)1024 * NE * 2);
    float* msgP   = (float*)alloc((size_t)8 * 1024 * H * 4);
    float* agg    = (float*)alloc((size_t)N_NODES * H * 4);
    short* WqT = (short*)alloc((size_t)HH * H * 2);
    short* WkT = (short*)alloc((size_t)HH * H * 2);
    short* WvT = (short*)alloc((size_t)HH * H * 2);
    short* liT = (short*)alloc((size_t)H * H * 2);
    short* ljT = (short*)alloc((size_t)H * H * 2);
    short* elT = (short*)alloc((size_t)HH * 3 * H * 2);
    short* rlT = (short*)alloc((size_t)HH * RBFK * 2);
    short* olT = (short*)alloc((size_t)H * HH * 2);

    hipMemsetAsync(cnt, 0, N_NODES * 4, stream);
    hipMemsetAsync(agg, 0, (size_t)N_NODES * H * 4, stream);

    k_extract<<<NE / 256, 256, 0, stream>>>(edge_idx, src, tgt);
    k_hist   <<<NE / 256, 256, 0, stream>>>(src, cnt);
    k_scan   <<<1, N_NODES, 0, stream>>>(cnt, segStart, cursor);
    k_scatter<<<NE / 256, 256, 0, stream>>>(src, tgt, edge_weight, cursor, srcS, tgtS, ewS);
    k_build_ai<<<NE * H / 256, 256, 0, stream>>>(atom_embs, srcS, tgtS, ewS, aiB, ajB);
    k_rbf    <<<NE * RBFK / 256, 256, 0, stream>>>(srcS, tgtS, pos, rbfB);

    // weight transposes (f32 -> bf16, K-major)
    k_transpose_b<<<(H * HH + 255) / 256, 256, 0, stream>>>(Wq, WqT, H, HH);
    k_transpose_b<<<(H * HH + 255) / 256, 256, 0, stream>>>(Wk, WkT, H, HH);
    k_transpose_b<<<(H * HH + 255) / 256, 256, 0, stream>>>(Wv, WvT, H, HH);
    k_transpose_b<<<(H * H + 255) / 256, 256, 0, stream>>>(li_w, liT, H, H);
    k_transpose_b<<<(H * H + 255) / 256, 256, 0, stream>>>(lj_w, ljT, H, H);
    k_transpose_b<<<(3 * H * HH + 255) / 256, 256, 0, stream>>>(el_w, elT, 3 * H, HH);
    k_transpose_b<<<(RBFK * HH + 255) / 256, 256, 0, stream>>>(rl_w, rlT, RBFK, HH);
    k_transpose_b<<<(HH * H + 255) / 256, 256, 0, stream>>>(ol_w, olT, HH, H);

    // Q (scaled), K as bf16; V into f32 feats
    dim3 gQKV(HH / 128, NE / 128);
    mgemm<1><<<gQKV, 256, 0, stream>>>(aiB, H, WqT, H, QB, HH, H, 0.08838834764831845f, nullptr, 0, 0);
    mgemm<1><<<gQKV, 256, 0, stream>>>(aiB, H, WkT, H, KB, HH, H, 1.0f, nullptr, 0, 0);
    mgemm<0><<<gQKV, 256, 0, stream>>>(aiB, H, WvT, H, feats, HH, H, 1.0f, nullptr, 0, 0);

    // hi/hj (f32) -> eij (bf16)
    dim3 gHI(1, NE / 128);
    mgemm<0><<<gHI, 256, 0, stream>>>(aiB, H, liT, H, hi, H, H, 1.0f, li_b, 0, 0);
    mgemm<0><<<gHI, 256, 0, stream>>>(ajB, H, ljT, H, hj, H, H, 1.0f, lj_b, 0, 0);
    k_eij<<<NE * H / 256, 256, 0, stream>>>(hi, hj, eijB);

    // feats += eij@el + el_b ; feats += rbf@rl + rl_b
    mgemm<0><<<gQKV, 256, 0, stream>>>(eijB, 3 * H, elT, 3 * H, feats, HH, 3 * H, 1.0f, el_b, 1, 0);
    mgemm<0><<<gQKV, 256, 0, stream>>>(rbfB, RBFK, rlT, RBFK, feats, HH, RBFK, 1.0f, rl_b, 1, 0);
    k_f2b<<<NE * HH / 256, 256, 0, stream>>>(feats, featsB, NE * HH);

    // GT[j,i] = sum_k olT[j,k]*featsB[i,k]  ->  GT = G^T (H x NE)
    dim3 gGT(NE / 128, 1);
    mgemm<1><<<gGT, 256, 0, stream>>>(olT, HH, featsB, HH, GT, NE, HH, 1.0f, nullptr, 0, 0);

    // logits / softmax / msg in 4 row-blocks of 1024
    for (int rb = 0; rb < 4; rb++) {
        const short* Qrb = QB + (size_t)rb * 1024 * HH;
        dim3 gL(NE / 128, 1024 / 128);
        mgemm<0><<<gL, 256, 0, stream>>>(Qrb, HH, KB, HH, Lt, NE, HH, 1.0f, nullptr, 0, 0);
        k_softmax_b<<<1024, 256, 0, stream>>>(Lt, prodB, segStart);
        // msg_rb = prodB @ GT^T, split-K=8 into 8 partial buffers
        dim3 gM(H / 128, 1024 / 128, 8);
        mgemm<0><<<gM, 256, 0, stream>>>(prodB, NE, GT, NE, msgP, H, NE, 1.0f, nullptr, 0, (long)1024 * H);
        k_scatter_rb<<<1024 * H / 256, 256, 0, stream>>>(tgtS, msgP, ol_b, agg, rb * 1024);
    }

    k_head<<<N_NODES, H, 0, stream>>>(agg, ln_g, ln_b, f1_w, f1_b, f2_w, f2_b, f3_w, f3_b, out);
}

// Round 3
// 319.144 us; speedup vs baseline: 12.3670x; 1.5589x over previous
//
#include <hip/hip_runtime.h>
#include <math.h>

#define N_NODES 512
#define NE      4096
#define H       128
#define HH      1024
#define RBFK    64
#define KCAT    576   // 128 (ai) + 384 (eij) + 64 (rbf)

typedef __attribute__((ext_vector_type(8))) short bf16x8;
typedef __attribute__((ext_vector_type(4))) float f32x4;

__device__ __forceinline__ short f2bf(float x) {
    unsigned u = __builtin_bit_cast(unsigned, x);
    unsigned r = u + 0x7FFFu + ((u >> 16) & 1u);   // RNE
    return (short)(r >> 16);
}

__device__ __forceinline__ void gload16(const short* g, short* l) {
    __builtin_amdgcn_global_load_lds(
        (const __attribute__((address_space(1))) void*)g,
        (__attribute__((address_space(3))) void*)l, 16, 0, 0);
}

// ---------------- prep ----------------

__global__ void k_extract(const int* __restrict__ ei, int* __restrict__ src, int* __restrict__ tgt) {
    __shared__ int s_is64;
    if (threadIdx.x == 0) {
        int any = 0;
        for (int i = 1; i < 128; i += 2) any |= ei[i];
        s_is64 = (any == 0) ? 1 : 0;
    }
    __syncthreads();
    int e = blockIdx.x * blockDim.x + threadIdx.x;
    if (e < NE) {
        if (s_is64) { src[e] = ei[2 * e]; tgt[e] = ei[2 * NE + 2 * e]; }
        else        { src[e] = ei[e];     tgt[e] = ei[NE + e];         }
    }
}

// single block: histogram + scan (hist folded in, no global cnt / memset)
__global__ void k_scan(const int* __restrict__ src, int* __restrict__ segStart, int* __restrict__ cursor) {
    __shared__ int s[N_NODES];
    int t = threadIdx.x;
    s[t] = 0;
    __syncthreads();
    for (int e = t; e < NE; e += N_NODES) atomicAdd(&s[src[e]], 1);
    __syncthreads();
    int cntv = s[t];
    __syncthreads();
    for (int off = 1; off < N_NODES; off <<= 1) {
        int v = (t >= off) ? s[t - off] : 0;
        __syncthreads();
        s[t] += v;
        __syncthreads();
    }
    segStart[t + 1] = s[t];
    if (t == 0) segStart[0] = 0;
    cursor[t] = s[t] - cntv;
}

__global__ void k_scatter(const int* __restrict__ src, const int* __restrict__ tgt,
                          const float* __restrict__ ew, int* __restrict__ cursor,
                          int* __restrict__ srcS, int* __restrict__ tgtS, float* __restrict__ ewS) {
    int e = blockIdx.x * blockDim.x + threadIdx.x;
    if (e < NE) {
        int n = src[e];
        int p = atomicAdd(&cursor[n], 1);
        srcS[p] = n;
        tgtS[p] = tgt[e];
        ewS[p]  = ew[e];
    }
}

// ai -> Acat[:,0:128], aj -> ajB, rbf -> Acat[:,512:576]
__global__ void k_prep2(const float* __restrict__ atom_embs, const float* __restrict__ pos,
                        const int* __restrict__ srcS, const int* __restrict__ tgtS,
                        const float* __restrict__ ewS,
                        short* __restrict__ Acat, short* __restrict__ ajB) {
    int idx = blockIdx.x * blockDim.x + threadIdx.x;   // NE*H
    int p = idx >> 7, h = idx & 127;
    if (p >= NE) return;
    int s = srcS[p], t = tgtS[p];
    float ew = ewS[p];
    Acat[(size_t)p * KCAT + h] = f2bf(atom_embs[t * H + h] + ew);
    ajB[idx] = f2bf(atom_embs[s * H + h] + ew);
    if (h < RBFK) {
        float dx = pos[t * 3 + 0] - pos[s * 3 + 0];
        float dy = pos[t * 3 + 1] - pos[s * 3 + 1];
        float dz = pos[t * 3 + 2] - pos[s * 3 + 2];
        float d = sqrtf(dx * dx + dy * dy + dz * dz);
        float x = d * 0.1f;
        float cut = 0.0f;
        if (x < 1.0f) {
            float x3 = x * x * x, x4 = x3 * x, x5 = x4 * x;
            cut = 1.0f - 6.0f * x5 + 15.0f * x4 - 10.0f * x3;
        }
        float ck = 1.0f + (float)h * (-0.015872295239210119f);
        float tt = expf(-d) - ck;
        Acat[(size_t)p * KCAT + 512 + h] = f2bf(cut * expf(-1024.0929857f * tt * tt));
    }
}

// all weight transposes + bias_sum in ONE kernel
__global__ void k_transpose_all(
    const float* __restrict__ Wq, const float* __restrict__ Wk, const float* __restrict__ Wv,
    const float* __restrict__ li_w, const float* __restrict__ lj_w,
    const float* __restrict__ el_w, const float* __restrict__ rl_w, const float* __restrict__ ol_w,
    const float* __restrict__ el_b, const float* __restrict__ rl_b,
    short* __restrict__ WqkT, short* __restrict__ Bcat,
    short* __restrict__ liT, short* __restrict__ ljT, short* __restrict__ olT,
    float* __restrict__ bias_sum)
{
    int idx = blockIdx.x * blockDim.x + threadIdx.x;
    if (idx < 262144) {                      // WqkT: [2048 x 128]
        int n = idx >> 7, k = idx & 127;
        float v = (n < 1024) ? Wq[k * HH + n] : Wk[k * HH + (n - 1024)];
        WqkT[idx] = f2bf(v);
        return;
    }
    idx -= 262144;
    if (idx < 589824) {                      // Bcat: [1024 x 576]
        int n = idx / KCAT, k = idx - n * KCAT;
        float v = (k < 128) ? Wv[k * HH + n]
                : (k < 512) ? el_w[(k - 128) * HH + n]
                            : rl_w[(k - 512) * HH + n];
        Bcat[idx] = f2bf(v);
        return;
    }
    idx -= 589824;
    if (idx < 32768) {                       // liT / ljT: [128 x 128] each
        int which = idx >> 14, r = idx & 16383;
        int n = r >> 7, k = r & 127;
        (which ? ljT : liT)[r] = f2bf((which ? lj_w : li_w)[k * H + n]);
        return;
    }
    idx -= 32768;
    if (idx < 131072) {                      // olT: [128 x 1024]
        int j = idx >> 10, k = idx & 1023;
        olT[idx] = f2bf(ol_w[k * H + j]);
        return;
    }
    idx -= 131072;
    if (idx < 1024) bias_sum[idx] = el_b[idx] + rl_b[idx];
}

// ---------------- bf16 MFMA NT GEMM (m97 structure) ----------------
template<int OUTB>
__global__ __launch_bounds__(256) void mgemm(
    const short* __restrict__ A, int lda,
    const short* __restrict__ B, int ldb,
    void* __restrict__ Cp, int ldc,
    int K, float alpha, const float* __restrict__ bias,
    long split_pitch)
{
    __shared__ __align__(16) short As[128 * 64];
    __shared__ __align__(16) short Bs[128 * 64];
    const int tid = threadIdx.x;
    const int wave = tid >> 6, lane = tid & 63;
    const int row0 = blockIdx.y * 128, col0 = blockIdx.x * 128;
    const int kchunk = K / gridDim.z;
    const int kbeg = kchunk * blockIdx.z;
    const int kend = kbeg + kchunk;

    f32x4 acc[4][4];
#pragma unroll
    for (int i = 0; i < 4; i++)
#pragma unroll
        for (int j = 0; j < 4; j++) acc[i][j] = (f32x4){0.f, 0.f, 0.f, 0.f};

    const int m0 = (wave >> 1) * 64, n0 = (wave & 1) * 64;
    const int lr = lane >> 3;
    const int lc = (lane & 7) * 8;
    const int cl = lane & 15, quad = lane >> 4;

    for (int k0 = kbeg; k0 < kend; k0 += 64) {
#pragma unroll
        for (int i = 0; i < 4; i++) {
            int r = wave * 32 + i * 8;
            gload16(A + (size_t)(row0 + r + lr) * lda + k0 + lc, As + r * 64);
            gload16(B + (size_t)(col0 + r + lr) * ldb + k0 + lc, Bs + r * 64);
        }
        __syncthreads();
#pragma unroll
        for (int kk = 0; kk < 64; kk += 32) {
            bf16x8 af[4], bf[4];
            int ko = kk + quad * 8;
#pragma unroll
            for (int i = 0; i < 4; i++)
                af[i] = *(const bf16x8*)(As + (m0 + i * 16 + cl) * 64 + ko);
#pragma unroll
            for (int j = 0; j < 4; j++)
                bf[j] = *(const bf16x8*)(Bs + (n0 + j * 16 + cl) * 64 + ko);
#pragma unroll
            for (int i = 0; i < 4; i++)
#pragma unroll
                for (int j = 0; j < 4; j++)
                    acc[i][j] = __builtin_amdgcn_mfma_f32_16x16x32_bf16(af[i], bf[j], acc[i][j], 0, 0, 0);
        }
        __syncthreads();
    }

    if (OUTB) {
        short* C = (short*)Cp;
#pragma unroll
        for (int i = 0; i < 4; i++)
#pragma unroll
            for (int j = 0; j < 4; j++) {
                int cc = col0 + n0 + j * 16 + cl;
                float bv = bias ? bias[cc] : 0.0f;
#pragma unroll
                for (int reg = 0; reg < 4; reg++) {
                    int rr = row0 + m0 + i * 16 + quad * 4 + reg;
                    C[(size_t)rr * ldc + cc] = f2bf(acc[i][j][reg] * alpha + bv);
                }
            }
    } else {
        float* C = (float*)Cp + (size_t)blockIdx.z * split_pitch;
#pragma unroll
        for (int i = 0; i < 4; i++)
#pragma unroll
            for (int j = 0; j < 4; j++) {
                int cc = col0 + n0 + j * 16 + cl;
#pragma unroll
                for (int reg = 0; reg < 4; reg++) {
                    int rr = row0 + m0 + i * 16 + quad * 4 + reg;
                    C[(size_t)rr * ldc + cc] = acc[i][j][reg] * alpha;
                }
            }
    }
}

// ---------------- fused hi/hj/eij (writes Acat cols 128..511) ----------------
__global__ __launch_bounds__(256) void k_edgefeat(
    const short* __restrict__ Acat_in, const short* __restrict__ ajB,
    const short* __restrict__ liT, const short* __restrict__ ljT,
    const float* __restrict__ li_b, const float* __restrict__ lj_b,
    short* __restrict__ Acat)
{
    __shared__ __align__(16) short As[128 * 128];
    __shared__ __align__(16) short Bs[128 * 128];
    const int tid = threadIdx.x;
    const int wave = tid >> 6, lane = tid & 63;
    const int row0 = blockIdx.x * 128;
    const int cl = lane & 15, quad = lane >> 4;
    const int m0 = (wave >> 1) * 64, n0 = (wave & 1) * 64;
    const int sr = lane >> 4, sc = (lane & 15) * 8;

    f32x4 ai_acc[4][4], aj_acc[4][4];
#pragma unroll
    for (int i = 0; i < 4; i++)
#pragma unroll
        for (int j = 0; j < 4; j++) {
            ai_acc[i][j] = (f32x4){0.f, 0.f, 0.f, 0.f};
            aj_acc[i][j] = (f32x4){0.f, 0.f, 0.f, 0.f};
        }

    // phase 1: hi = ai @ liT^T
#pragma unroll
    for (int i = 0; i < 8; i++) {
        int r = wave * 32 + i * 4;
        gload16(Acat_in + (size_t)(row0 + r + sr) * KCAT + sc, As + r * 128);
        gload16(liT + (r + sr) * 128 + sc, Bs + r * 128);
    }
    __syncthreads();
#pragma unroll
    for (int kk = 0; kk < 128; kk += 32) {
        bf16x8 af[4], bf[4];
        int ko = kk + quad * 8;
#pragma unroll
        for (int i = 0; i < 4; i++) af[i] = *(const bf16x8*)(As + (m0 + i * 16 + cl) * 128 + ko);
#pragma unroll
        for (int j = 0; j < 4; j++) bf[j] = *(const bf16x8*)(Bs + (n0 + j * 16 + cl) * 128 + ko);
#pragma unroll
        for (int i = 0; i < 4; i++)
#pragma unroll
            for (int j = 0; j < 4; j++)
                ai_acc[i][j] = __builtin_amdgcn_mfma_f32_16x16x32_bf16(af[i], bf[j], ai_acc[i][j], 0, 0, 0);
    }
    __syncthreads();
    // phase 2: hj = aj @ ljT^T
#pragma unroll
    for (int i = 0; i < 8; i++) {
        int r = wave * 32 + i * 4;
        gload16(ajB + (size_t)(row0 + r + sr) * 128 + sc, As + r * 128);
        gload16(ljT + (r + sr) * 128 + sc, Bs + r * 128);
    }
    __syncthreads();
#pragma unroll
    for (int kk = 0; kk < 128; kk += 32) {
        bf16x8 af[4], bf[4];
        int ko = kk + quad * 8;
#pragma unroll
        for (int i = 0; i < 4; i++) af[i] = *(const bf16x8*)(As + (m0 + i * 16 + cl) * 128 + ko);
#pragma unroll
        for (int j = 0; j < 4; j++) bf[j] = *(const bf16x8*)(Bs + (n0 + j * 16 + cl) * 128 + ko);
#pragma unroll
        for (int i = 0; i < 4; i++)
#pragma unroll
            for (int j = 0; j < 4; j++)
                aj_acc[i][j] = __builtin_amdgcn_mfma_f32_16x16x32_bf16(af[i], bf[j], aj_acc[i][j], 0, 0, 0);
    }
    // epilogue: eij = [hi+hj, hi-hj, hi*hj] into Acat cols 128..511
#pragma unroll
    for (int i = 0; i < 4; i++)
#pragma unroll
        for (int j = 0; j < 4; j++) {
            int cc = n0 + j * 16 + cl;
            float bi = li_b[cc], bj = lj_b[cc];
#pragma unroll
            for (int reg = 0; reg < 4; reg++) {
                int rr = row0 + m0 + i * 16 + quad * 4 + reg;
                float hv = ai_acc[i][j][reg] + bi;
                float gv = aj_acc[i][j][reg] + bj;
                short* rowp = Acat + (size_t)rr * KCAT;
                rowp[128 + cc] = f2bf(hv + gv);
                rowp[256 + cc] = f2bf(hv - gv);
                rowp[384 + cc] = f2bf(hv * gv);
            }
        }
}

// ---------------- segment softmax (contiguous column segments), bf16 out ----------------
__global__ __launch_bounds__(256) void k_softmax_b(const float* __restrict__ L,
                                                   short* __restrict__ P,
                                                   const int* __restrict__ segStart) {
    __shared__ float row[NE];
    const float* lr = L + (size_t)blockIdx.x * NE;
    for (int i = threadIdx.x; i < NE; i += 256) row[i] = lr[i];
    __syncthreads();
    for (int n = threadIdx.x; n < N_NODES; n += 256) {
        int a = segStart[n], b = segStart[n + 1];
        if (a >= b) continue;
        float m = -1e30f;
        for (int p = a; p < b; p++) m = fmaxf(m, row[p]);
        float s = 0.0f;
        for (int p = a; p < b; p++) { float e = expf(row[p] - m); row[p] = e; s += e; }
        float inv = 1.0f / s;
        for (int p = a; p < b; p++) row[p] *= inv;
    }
    __syncthreads();
    short* pr = P + (size_t)blockIdx.x * NE;
    for (int i = threadIdx.x; i < NE; i += 256) pr[i] = f2bf(row[i]);
}

// sum 8 split-K partials + ol_b, scatter-add into agg by tgt
__global__ void k_scatter_rb(const int* __restrict__ tgtS, const float* __restrict__ msgP,
                             const float* __restrict__ ol_b, float* __restrict__ agg) {
    int idx = blockIdx.x * blockDim.x + threadIdx.x;   // NE*H
    int p = idx >> 7, h = idx & 127;
    if (p >= NE) return;
    float s = ol_b[h];
#pragma unroll
    for (int z = 0; z < 8; z++) s += msgP[(size_t)z * NE * H + idx];
    atomicAdd(&agg[tgtS[p] * H + h], s);
}

// ---------------- LN + FFN + LN head ----------------
__global__ __launch_bounds__(128) void k_head(
    const float* __restrict__ agg,
    const float* __restrict__ ln_g, const float* __restrict__ ln_b,
    const float* __restrict__ f1_w, const float* __restrict__ f1_b,
    const float* __restrict__ f2_w, const float* __restrict__ f2_b,
    const float* __restrict__ f3_w, const float* __restrict__ f3_b,
    float* __restrict__ out)
{
    __shared__ float x[H];
    __shared__ float red[H];
    int t = threadIdx.x, row = blockIdx.x;
    float v = agg[row * H + t];
    red[t] = v; __syncthreads();
    for (int s = 64; s > 0; s >>= 1) { if (t < s) red[t] += red[t + s]; __syncthreads(); }
    float mu = red[0] * (1.0f / H); __syncthreads();
    float dv = v - mu;
    red[t] = dv * dv; __syncthreads();
    for (int s = 64; s > 0; s >>= 1) { if (t < s) red[t] += red[t + s]; __syncthreads(); }
    float var = red[0] * (1.0f / H); __syncthreads();
    x[t] = dv * rsqrtf(var + 1e-5f) * ln_g[t] + ln_b[t];
    __syncthreads();
    const float* Ws[3] = { f1_w, f2_w, f3_w };
    const float* Bb[3] = { f1_b, f2_b, f3_b };
    for (int l = 0; l < 3; l++) {
        float acc = Bb[l][t];
        const float* Wl = Ws[l];
        for (int k = 0; k < H; k++) acc = fmaf(x[k], Wl[k * H + t], acc);
        float o = fmaxf(acc, 0.0f) + log1pf(expf(-fabsf(acc)));
        __syncthreads();
        x[t] = o;
        __syncthreads();
    }
    float xv = x[t];
    red[t] = xv; __syncthreads();
    for (int s = 64; s > 0; s >>= 1) { if (t < s) red[t] += red[t + s]; __syncthreads(); }
    mu = red[0] * (1.0f / H); __syncthreads();
    float dv2 = xv - mu;
    red[t] = dv2 * dv2; __syncthreads();
    for (int s = 64; s > 0; s >>= 1) { if (t < s) red[t] += red[t + s]; __syncthreads(); }
    var = red[0] * (1.0f / H);
    out[row * H + t] = dv2 * rsqrtf(var + 1e-5f) * ln_g[t] + ln_b[t];
}

// ---------------- launch ----------------

extern "C" void kernel_launch(void* const* d_in, const int* in_sizes, int n_in,
                              void* d_out, int out_size, void* d_ws, size_t ws_size,
                              hipStream_t stream) {
    const float* atom_embs   = (const float*)d_in[0];
    const float* pos         = (const float*)d_in[1];
    const float* edge_weight = (const float*)d_in[2];
    const int*   edge_idx    = (const int*)d_in[3];
    const float* Wq   = (const float*)d_in[4];
    const float* Wk   = (const float*)d_in[5];
    const float* Wv   = (const float*)d_in[6];
    const float* li_w = (const float*)d_in[7];
    const float* li_b = (const float*)d_in[8];
    const float* lj_w = (const float*)d_in[9];
    const float* lj_b = (const float*)d_in[10];
    const float* el_w = (const float*)d_in[11];
    const float* el_b = (const float*)d_in[12];
    const float* rl_w = (const float*)d_in[13];
    const float* rl_b = (const float*)d_in[14];
    const float* ol_w = (const float*)d_in[15];
    const float* ol_b = (const float*)d_in[16];
    const float* ln_g = (const float*)d_in[17];
    const float* ln_b = (const float*)d_in[18];
    const float* f1_w = (const float*)d_in[19];
    const float* f1_b = (const float*)d_in[20];
    const float* f2_w = (const float*)d_in[21];
    const float* f2_b = (const float*)d_in[22];
    const float* f3_w = (const float*)d_in[23];
    const float* f3_b = (const float*)d_in[24];
    float* out = (float*)d_out;

    char* w = (char*)d_ws;
    size_t off = 0;
    auto alloc = [&](size_t bytes) -> void* {
        void* p = w + off;
        off += (bytes + 255) & ~(size_t)255;
        return p;
    };
    int*   src      = (int*)alloc(NE * 4);
    int*   tgt      = (int*)alloc(NE * 4);
    int*   srcS     = (int*)alloc(NE * 4);
    int*   tgtS     = (int*)alloc(NE * 4);
    float* ewS      = (float*)alloc(NE * 4);
    int*   cursor   = (int*)alloc(N_NODES * 4);
    int*   segStart = (int*)alloc((N_NODES + 1) * 4);
    short* Acat   = (short*)alloc((size_t)NE * KCAT * 2);
    short* ajB    = (short*)alloc((size_t)NE * H * 2);
    short* WqkT   = (short*)alloc((size_t)2048 * H * 2);
    short* Bcat   = (short*)alloc((size_t)HH * KCAT * 2);
    short* liT    = (short*)alloc((size_t)H * H * 2);
    short* ljT    = (short*)alloc((size_t)H * H * 2);
    short* olT    = (short*)alloc((size_t)H * HH * 2);
    float* bias_sum = (float*)alloc(HH * 4);
    short* QKB    = (short*)alloc((size_t)NE * 2048 * 2);
    short* featsB = (short*)alloc((size_t)NE * HH * 2);
    short* GT     = (short*)alloc((size_t)H * NE * 2);
    float* Lt     = (float*)alloc((size_t)NE * NE * 4);
    short* prodB  = (short*)alloc((size_t)NE * NE * 2);
    float* msgP   = (float*)alloc((size_t)8 * NE * H * 4);
    float* agg    = (float*)alloc((size_t)N_NODES * H * 4);

    hipMemsetAsync(agg, 0, (size_t)N_NODES * H * 4, stream);

    k_extract<<<NE / 256, 256, 0, stream>>>(edge_idx, src, tgt);
    k_scan   <<<1, N_NODES, 0, stream>>>(src, segStart, cursor);
    k_scatter<<<NE / 256, 256, 0, stream>>>(src, tgt, edge_weight, cursor, srcS, tgtS, ewS);
    k_prep2  <<<NE * H / 256, 256, 0, stream>>>(atom_embs, pos, srcS, tgtS, ewS, Acat, ajB);
    k_transpose_all<<<(1016832 + 255) / 256, 256, 0, stream>>>(
        Wq, Wk, Wv, li_w, lj_w, el_w, rl_w, ol_w, el_b, rl_b,
        WqkT, Bcat, liT, ljT, olT, bias_sum);

    // fused hi/hj/eij -> Acat cols 128..511
    k_edgefeat<<<NE / 128, 256, 0, stream>>>(Acat, ajB, liT, ljT, li_b, lj_b, Acat);

    // QK: [NE x 2048] bf16 (Q unscaled; scale folded into logits alpha)
    {
        dim3 g(2048 / 128, NE / 128);
        mgemm<1><<<g, 256, 0, stream>>>(Acat, KCAT, WqkT, H, QKB, 2048, H, 1.0f, nullptr, 0);
    }
    // feats = ai@Wv + eij@el + rbf@rl + (el_b+rl_b), bf16 out, ONE GEMM K=576
    {
        dim3 g(HH / 128, NE / 128);
        mgemm<1><<<g, 256, 0, stream>>>(Acat, KCAT, Bcat, KCAT, featsB, HH, KCAT, 1.0f, bias_sum, 0);
    }
    // GT = (feats @ ol_w)^T : [H x NE] bf16
    {
        dim3 g(NE / 128, 1);
        mgemm<1><<<g, 256, 0, stream>>>(olT, HH, featsB, HH, GT, NE, HH, 1.0f, nullptr, 0);
    }
    // logits = alpha * Q @ K^T : [NE x NE] f32, single launch
    {
        dim3 g(NE / 128, NE / 128);
        mgemm<0><<<g, 256, 0, stream>>>(QKB, 2048, QKB + 1024, 2048, Lt, NE, HH,
                                        0.08838834764831845f, nullptr, 0);
    }
    k_softmax_b<<<NE, 256, 0, stream>>>(Lt, prodB, segStart);
    // msg = prod @ GT^T : [NE x H], split-K=8
    {
        dim3 g(1, NE / 128, 8);
        mgemm<0><<<g, 256, 0, stream>>>(prodB, NE, GT, NE, msgP, H, NE, 1.0f, nullptr,
                                        (long)NE * H);
    }
    k_scatter_rb<<<NE * H / 256, 256, 0, stream>>>(tgtS, msgP, ol_b, agg);
    k_head<<<N_NODES, H, 0, stream>>>(agg, ln_g, ln_b, f1_w, f1_b, f2_w, f2_b, f3_w, f3_b, out);
}